// Round 13
// baseline (1258.001 us; speedup 1.0000x reference)
//
#include <hip/hip_runtime.h>
#include <math.h>

#define N_NODES 100000
#define N_EDGES 1600000
#define D_IN 64
#define D_HID 128

#define BKT_SHIFT 9
#define BKT_NODES 512
#define NB ((N_NODES + BKT_NODES - 1) / BKT_NODES)  // 196
#define CAP 16384                                    // per-bucket capacity (mean ~8163)
#define CHUNK 8192
#define BIN_T 1024
#define FILL_T 1024

#define AG_T 1024
#define AG_NODES 128
#define AG_NBLK ((N_NODES + AG_NODES - 1) / AG_NODES)  // 782

// packed edge: bits 0..16 = row (src node), bits 17..25 = dst & 511
#define PACK(row, col) (((unsigned)((col) & (BKT_NODES - 1)) << 17) | (unsigned)(row))
#define P_ROW(u) ((int)((u) & 0x1FFFFu))
#define P_DST(u) ((int)(((u) >> 17) & 0x1FFu))

static __device__ __forceinline__ unsigned short f2bf(float f) {
    unsigned int u = __float_as_uint(f);
    u += 0x7FFFu + ((u >> 16) & 1u);  // round-to-nearest-even
    return (unsigned short)(u >> 16);
}

// ---------------- phase 1: LDS counting-sort edges into 196 col-buckets ------

__global__ __launch_bounds__(BIN_T) void k_bin(const int* __restrict__ row,
                                               const int* __restrict__ col,
                                               int* __restrict__ gcur,
                                               unsigned* __restrict__ pairs) {
    __shared__ int bcnt[NB];
    __shared__ int boff[NB];
    __shared__ int gbase[NB];
    __shared__ int sc[256];
    __shared__ unsigned stage[CHUNK];          // 32 KB
    __shared__ unsigned char bkt_of[CHUNK];    // 8 KB
    const int t = threadIdx.x;
    const int e0 = blockIdx.x * CHUNK;
    const int nE = min(CHUNK, N_EDGES - e0);

    for (int i = t; i < NB; i += BIN_T) bcnt[i] = 0;
    __syncthreads();

    int myb[8], myrank[8], myr[8];
#pragma unroll
    for (int k = 0; k < 8; ++k) {
        const int i = t + k * BIN_T;
        if (i < nE) {
            myr[k] = row[e0 + i];
            const int c = col[e0 + i];
            myb[k] = c >> BKT_SHIFT;
            myrank[k] = atomicAdd(&bcnt[myb[k]], 1);
            myr[k] = PACK(myr[k], c);
        }
    }
    __syncthreads();

    if (t < 256) sc[t] = (t < NB) ? bcnt[t] : 0;
    __syncthreads();
    for (int off = 1; off < 256; off <<= 1) {
        int v = 0;
        if (t < 256 && t >= off) v = sc[t - off];
        __syncthreads();
        if (t < 256) sc[t] += v;
        __syncthreads();
    }
    if (t < NB) {
        boff[t] = sc[t] - bcnt[t];
        if (bcnt[t] > 0) gbase[t] = atomicAdd(&gcur[t], bcnt[t]);
    }
    __syncthreads();

    // stage into bucket-sorted order in LDS; record bucket per slot inline
#pragma unroll
    for (int k = 0; k < 8; ++k) {
        const int i = t + k * BIN_T;
        if (i < nE) {
            const int pos = boff[myb[k]] + myrank[k];
            stage[pos] = (unsigned)myr[k];
            bkt_of[pos] = (unsigned char)myb[k];
        }
    }
    __syncthreads();

    for (int s = t; s < nE; s += BIN_T) {
        const int b = bkt_of[s];
        pairs[(size_t)b * CAP + gbase[b] + (s - boff[b])] = stage[s];
    }
}

// ---------------- phase 2: per-bucket hist + scan + dense fill + xb ----------

__global__ __launch_bounds__(FILL_T) void k_fill2(const unsigned* __restrict__ pairs,
                                                  const int* __restrict__ gcur,
                                                  const float* __restrict__ x,
                                                  int* __restrict__ offsets,
                                                  float* __restrict__ dinv,
                                                  int* __restrict__ src,
                                                  unsigned short* __restrict__ xb) {
    __shared__ unsigned stage[CAP];      // 64 KB
    __shared__ int ncnt[BKT_NODES];
    __shared__ int ncur[BKT_NODES];
    __shared__ int sc[BKT_NODES];
    __shared__ int scb[256];
    const int b = blockIdx.x, t = threadIdx.x;
    const int base = b << BKT_SHIFT;
    const int nNodes = min(BKT_NODES, N_NODES - base);

    // redundant scan of the 196 bucket counts -> this block's global base
    if (t < 256) scb[t] = (t < NB) ? gcur[t] : 0;
    __syncthreads();
    for (int off = 1; off < 256; off <<= 1) {
        int v = 0;
        if (t < 256 && t >= off) v = scb[t - off];
        __syncthreads();
        if (t < 256) scb[t] += v;
        __syncthreads();
    }
    const int nE = gcur[b];
    const int gb = scb[b] - nE;  // exclusive prefix
    if (b == 0 && t == 0) offsets[N_NODES] = scb[NB - 1];

    const unsigned* bp = pairs + (size_t)b * CAP;
    for (int i = t; i < nE; i += FILL_T) stage[i] = bp[i];
    for (int i = t; i < BKT_NODES; i += FILL_T) ncnt[i] = 0;
    __syncthreads();

    for (int i = t; i < nE; i += FILL_T) atomicAdd(&ncnt[P_DST(stage[i])], 1);
    __syncthreads();

    const int c = (t < BKT_NODES) ? ncnt[t] : 0;
    if (t < BKT_NODES) sc[t] = c;
    __syncthreads();
    for (int off = 1; off < BKT_NODES; off <<= 1) {
        int u = 0;
        if (t < BKT_NODES && t >= off) u = sc[t - off];
        __syncthreads();
        if (t < BKT_NODES) sc[t] += u;
        __syncthreads();
    }
    if (t < BKT_NODES) {
        const int o = gb + sc[t] - c;  // exclusive
        if (t < nNodes) {
            offsets[base + t] = o;
            dinv[base + t] = rsqrtf((float)c + 1.0f);
        }
        ncur[t] = o;
    }
    __syncthreads();

    for (int i = t; i < nE; i += FILL_T) {
        const unsigned u = stage[i];
        const int pos = atomicAdd(&ncur[P_DST(u)], 1);
        src[pos] = P_ROW(u);
    }

    // xb = bf16(dinv * |x|) for this bucket's nodes (ncnt still holds degrees)
    for (int i = t; i < nNodes * (D_IN / 4); i += FILL_T) {
        const int nl = i >> 4;           // local node
        const int q = i & 15;            // float4 index within row
        const float di = rsqrtf((float)ncnt[nl] + 1.0f);
        const float4 v = ((const float4*)(x + (size_t)(base + nl) * D_IN))[q];
        ushort4 o4;
        o4.x = f2bf(di * fabsf(v.x));
        o4.y = f2bf(di * fabsf(v.y));
        o4.z = f2bf(di * fabsf(v.z));
        o4.w = f2bf(di * fabsf(v.w));
        *(ushort4*)(xb + (size_t)(base + nl) * D_IN + q * 4) = o4;
    }
}

// ---------------- fused aggregate + GEMM + epilogue -> z ----------------
// Block: 1024 threads, 128 nodes.
// Phase A: 8 nodes/wave (slot=lane>>3, dc=lane&7), gather xb rows, f32 acc;
//          store to xs[k][node] with XOR swizzle (node ^ (dc<<3)) -> 2-way banks.
// Phase B: GEMM g = agg @ W1 from LDS; h=relu(di*g+b1); z = di*(h.W2).
// NOTE: all accumulators are named float4 scalars with static member access —
// runtime-indexed arrays / pointer-selects go to scratch (R12 post-mortem).

#define ACC8(v)                                                 \
    do {                                                        \
        a0 += __uint_as_float((v).x << 16);                     \
        a1 += __uint_as_float((v).x & 0xFFFF0000u);             \
        a2 += __uint_as_float((v).y << 16);                     \
        a3 += __uint_as_float((v).y & 0xFFFF0000u);             \
        a4 += __uint_as_float((v).z << 16);                     \
        a5 += __uint_as_float((v).z & 0xFFFF0000u);             \
        a6 += __uint_as_float((v).w << 16);                     \
        a7 += __uint_as_float((v).w & 0xFFFF0000u);             \
    } while (0)

// epilogue for one node: ca = dims 4tx..4tx+3, cb = dims 64+4tx..+3
#define EPILOGUE(nn, ca, cb)                                               \
    do {                                                                   \
        if ((nn) < N_NODES) {                                              \
            const float di = dinv[(nn)];                                   \
            float h, sv;                                                   \
            h = fmaxf(fmaf(di, (ca).x, b1a.x), 0.0f); sv = h * w2a.x;      \
            h = fmaxf(fmaf(di, (ca).y, b1a.y), 0.0f); sv = fmaf(h, w2a.y, sv); \
            h = fmaxf(fmaf(di, (ca).z, b1a.z), 0.0f); sv = fmaf(h, w2a.z, sv); \
            h = fmaxf(fmaf(di, (ca).w, b1a.w), 0.0f); sv = fmaf(h, w2a.w, sv); \
            h = fmaxf(fmaf(di, (cb).x, b1b.x), 0.0f); sv = fmaf(h, w2b.x, sv); \
            h = fmaxf(fmaf(di, (cb).y, b1b.y), 0.0f); sv = fmaf(h, w2b.y, sv); \
            h = fmaxf(fmaf(di, (cb).z, b1b.z), 0.0f); sv = fmaf(h, w2b.z, sv); \
            h = fmaxf(fmaf(di, (cb).w, b1b.w), 0.0f); sv = fmaf(h, w2b.w, sv); \
            sv += __shfl_xor(sv, 1, 64);                                   \
            sv += __shfl_xor(sv, 2, 64);                                   \
            sv += __shfl_xor(sv, 4, 64);                                   \
            sv += __shfl_xor(sv, 8, 64);                                   \
            if (tx == 0) z[(nn)] = di * sv;                                \
        }                                                                  \
    } while (0)

__global__ __launch_bounds__(AG_T) void k_agggemm(const int* __restrict__ offsets,
                                                  const int* __restrict__ src,
                                                  const unsigned short* __restrict__ xb,
                                                  const float* __restrict__ W1,
                                                  const float* __restrict__ dinv,
                                                  const float* __restrict__ b1,
                                                  const float* __restrict__ W2,
                                                  float* __restrict__ z) {
    __shared__ float ws[D_IN * D_HID];     // [k][dim]  32 KB
    __shared__ float xs[D_IN * AG_NODES];  // [k][node] swizzled, 32 KB
    const int t = threadIdx.x;
    const int n0 = blockIdx.x * AG_NODES;

    // stage W1 (2048 float4, 2 per thread)
    {
        const float4* W4 = (const float4*)W1;
        float4* ws4 = (float4*)ws;
        ws4[t] = W4[t];
        ws4[t + 1024] = W4[t + 1024];
    }

    // ---- Phase A: aggregation ----
    const int lane = t & 63;
    const int w = t >> 6;                 // wave 0..15
    const int slot = lane >> 3;           // node slot 0..7
    const int dc = lane & 7;              // dim chunk: dims 8*dc..8*dc+7
    const int nl = w * 8 + slot;          // local node 0..127
    const int n = n0 + nl;

    float a0 = 0, a1 = 0, a2 = 0, a3 = 0, a4 = 0, a5 = 0, a6 = 0, a7 = 0;

    if (n < N_NODES) {
        {   // self-loop term
            const uint4 v = ((const uint4*)(xb + (size_t)n * D_IN))[dc];
            ACC8(v);
        }
        const int s0 = offsets[n], s1 = offsets[n + 1];
        int j = s0;
        for (; j + 3 < s1; j += 4) {  // 4 gathers in flight per 8-lane group
            const int r0 = src[j];
            const int r1 = src[j + 1];
            const int r2 = src[j + 2];
            const int r3 = src[j + 3];
            const uint4 v0 = ((const uint4*)(xb + (size_t)r0 * D_IN))[dc];
            const uint4 v1 = ((const uint4*)(xb + (size_t)r1 * D_IN))[dc];
            const uint4 v2 = ((const uint4*)(xb + (size_t)r2 * D_IN))[dc];
            const uint4 v3 = ((const uint4*)(xb + (size_t)r3 * D_IN))[dc];
            ACC8(v0);
            ACC8(v1);
            ACC8(v2);
            ACC8(v3);
        }
        for (; j < s1; ++j) {
            const int r = src[j];
            const uint4 v = ((const uint4*)(xb + (size_t)r * D_IN))[dc];
            ACC8(v);
        }
    }

    // transpose to LDS: xs[(8*dc+q)*128 + (nl ^ (dc<<3))] = a_q
    {
        const int xi = nl ^ (dc << 3);
        float* xr = xs + dc * 8 * AG_NODES + xi;
        xr[0 * AG_NODES] = a0;
        xr[1 * AG_NODES] = a1;
        xr[2 * AG_NODES] = a2;
        xr[3 * AG_NODES] = a3;
        xr[4 * AG_NODES] = a4;
        xr[5 * AG_NODES] = a5;
        xr[6 * AG_NODES] = a6;
        xr[7 * AG_NODES] = a7;
    }
    __syncthreads();

    // ---- Phase B: GEMM ----
    const int tx = t & 15;   // dims {4tx..4tx+3} and {64+4tx..+3}
    const int ty = t >> 4;   // nodes {2ty, 2ty+1}

    float4 c0a = {0, 0, 0, 0}, c0b = {0, 0, 0, 0};  // node0: lo/hi dims
    float4 c1a = {0, 0, 0, 0}, c1b = {0, 0, 0, 0};  // node1

    const float4* ws4 = (const float4*)ws;
#pragma unroll
    for (int g = 0; g < 8; ++g) {
        const int X = g << 3;
        const float* xrow = xs + g * 8 * AG_NODES + ((2 * ty) ^ X);
#pragma unroll
        for (int q = 0; q < 8; ++q) {
            const int k = 8 * g + q;
            const float2 xv = *(const float2*)(xrow + q * AG_NODES);
            const float4 wa = ws4[k * 32 + tx];
            const float4 wb = ws4[k * 32 + 16 + tx];
            c0a.x = fmaf(xv.x, wa.x, c0a.x);
            c0a.y = fmaf(xv.x, wa.y, c0a.y);
            c0a.z = fmaf(xv.x, wa.z, c0a.z);
            c0a.w = fmaf(xv.x, wa.w, c0a.w);
            c0b.x = fmaf(xv.x, wb.x, c0b.x);
            c0b.y = fmaf(xv.x, wb.y, c0b.y);
            c0b.z = fmaf(xv.x, wb.z, c0b.z);
            c0b.w = fmaf(xv.x, wb.w, c0b.w);
            c1a.x = fmaf(xv.y, wa.x, c1a.x);
            c1a.y = fmaf(xv.y, wa.y, c1a.y);
            c1a.z = fmaf(xv.y, wa.z, c1a.z);
            c1a.w = fmaf(xv.y, wa.w, c1a.w);
            c1b.x = fmaf(xv.y, wb.x, c1b.x);
            c1b.y = fmaf(xv.y, wb.y, c1b.y);
            c1b.z = fmaf(xv.y, wb.z, c1b.z);
            c1b.w = fmaf(xv.y, wb.w, c1b.w);
        }
    }

    // epilogue (no address-taken arrays; two explicit expansions)
    const float4 b1a = ((const float4*)(b1 + 4 * tx))[0];
    const float4 b1b = ((const float4*)(b1 + 64 + 4 * tx))[0];
    const float4 w2a = ((const float4*)(W2 + 4 * tx))[0];
    const float4 w2b = ((const float4*)(W2 + 64 + 4 * tx))[0];
    EPILOGUE(n0 + 2 * ty, c0a, c0b);
    EPILOGUE(n0 + 2 * ty + 1, c1a, c1b);
}

// ---------------- layer 2 aggregate + final ----------------

__global__ void k_out(const int* __restrict__ offsets, const int* __restrict__ src,
                      const float* __restrict__ z, const float* __restrict__ dinv,
                      const float* __restrict__ b2, float* __restrict__ out, int n) {
    const int i = blockIdx.x * blockDim.x + threadIdx.x;
    if (i >= n) return;
    float s = z[i];  // self-loop
    const int s0 = offsets[i], s1 = offsets[i + 1];
    int j = s0;
    for (; j + 3 < s1; j += 4)
        s += z[src[j]] + z[src[j + 1]] + z[src[j + 2]] + z[src[j + 3]];
    for (; j < s1; ++j) s += z[src[j]];
    float v = fmaf(dinv[i], s, b2[0]);
    v = fmaxf(v, 0.0f);
    out[i] = 1.0f / (1.0f + expf(-v));
}

extern "C" void kernel_launch(void* const* d_in, const int* in_sizes, int n_in,
                              void* d_out, int out_size, void* d_ws, size_t ws_size,
                              hipStream_t stream) {
    const float* x  = (const float*)d_in[0];
    const int* ei   = (const int*)d_in[1];
    const float* W1 = (const float*)d_in[2];
    const float* b1 = (const float*)d_in[3];
    const float* W2 = (const float*)d_in[4];
    const float* b2 = (const float*)d_in[5];
    float* out = (float*)d_out;

    const int* row = ei;
    const int* col = ei + N_EDGES;

    // workspace layout
    char* p = (char*)d_ws;
    float* dinv          = (float*)p;          p += sizeof(float) * N_NODES;
    unsigned short* xb   = (unsigned short*)p; p += sizeof(unsigned short) * (size_t)N_NODES * D_IN;
    float* z             = (float*)p;          p += sizeof(float) * N_NODES;
    int* offsets         = (int*)p;            p += sizeof(int) * (N_NODES + 1);
    int* src             = (int*)p;            p += sizeof(int) * N_EDGES;
    int* gcur            = (int*)p;            p += sizeof(int) * NB;
    p = (char*)(((size_t)p + 15) & ~(size_t)15);
    unsigned* pairs      = (unsigned*)p;       p += sizeof(unsigned) * (size_t)NB * CAP;

    hipMemsetAsync(gcur, 0, sizeof(int) * NB, stream);
    k_bin<<<(N_EDGES + CHUNK - 1) / CHUNK, BIN_T, 0, stream>>>(row, col, gcur, pairs);
    k_fill2<<<NB, FILL_T, 0, stream>>>(pairs, gcur, x, offsets, dinv, src, xb);

    k_agggemm<<<AG_NBLK, AG_T, 0, stream>>>(offsets, src, xb, W1, dinv, b1, W2, z);

    k_out<<<(N_NODES + 255) / 256, 256, 0, stream>>>(offsets, src, z, dinv, b2, out, N_NODES);
}

// Round 14
// 136.664 us; speedup vs baseline: 9.2051x; 9.2051x over previous
//
#include <hip/hip_runtime.h>
#include <math.h>

#define N_NODES 100000
#define N_EDGES 1600000
#define D_IN 64
#define D_HID 128

#define BKT_SHIFT 9
#define BKT_NODES 512
#define NB ((N_NODES + BKT_NODES - 1) / BKT_NODES)  // 196
#define CAP 16384                                    // per-bucket capacity (mean ~8163)
#define CHUNK 8192
#define BIN_T 1024
#define FILL_T 1024

#define AG_T 256
#define AG_NODES 128
#define AG_NBLK ((N_NODES + AG_NODES - 1) / AG_NODES)  // 782

// packed edge: bits 0..16 = row (src node), bits 17..25 = dst & 511
#define PACK(row, col) (((unsigned)((col) & (BKT_NODES - 1)) << 17) | (unsigned)(row))
#define P_ROW(u) ((int)((u) & 0x1FFFFu))
#define P_DST(u) ((int)(((u) >> 17) & 0x1FFu))

static __device__ __forceinline__ unsigned short f2bf(float f) {
    unsigned int u = __float_as_uint(f);
    u += 0x7FFFu + ((u >> 16) & 1u);  // round-to-nearest-even
    return (unsigned short)(u >> 16);
}

// ---------------- phase 1: LDS counting-sort edges into 196 col-buckets ------

__global__ __launch_bounds__(BIN_T) void k_bin(const int* __restrict__ row,
                                               const int* __restrict__ col,
                                               int* __restrict__ gcur,
                                               unsigned* __restrict__ pairs) {
    __shared__ int bcnt[NB];
    __shared__ int boff[NB];
    __shared__ int gbase[NB];
    __shared__ int sc[256];
    __shared__ unsigned stage[CHUNK];          // 32 KB
    __shared__ unsigned char bkt_of[CHUNK];    // 8 KB
    const int t = threadIdx.x;
    const int e0 = blockIdx.x * CHUNK;
    const int nE = min(CHUNK, N_EDGES - e0);

    for (int i = t; i < NB; i += BIN_T) bcnt[i] = 0;
    __syncthreads();

    int myb[8], myrank[8], myr[8];
#pragma unroll
    for (int k = 0; k < 8; ++k) {
        const int i = t + k * BIN_T;
        if (i < nE) {
            myr[k] = row[e0 + i];
            const int c = col[e0 + i];
            myb[k] = c >> BKT_SHIFT;
            myrank[k] = atomicAdd(&bcnt[myb[k]], 1);
            myr[k] = PACK(myr[k], c);
        }
    }
    __syncthreads();

    if (t < 256) sc[t] = (t < NB) ? bcnt[t] : 0;
    __syncthreads();
    for (int off = 1; off < 256; off <<= 1) {
        int v = 0;
        if (t < 256 && t >= off) v = sc[t - off];
        __syncthreads();
        if (t < 256) sc[t] += v;
        __syncthreads();
    }
    if (t < NB) {
        boff[t] = sc[t] - bcnt[t];
        if (bcnt[t] > 0) gbase[t] = atomicAdd(&gcur[t], bcnt[t]);
    }
    __syncthreads();

    // stage into bucket-sorted order in LDS; record bucket per slot inline
#pragma unroll
    for (int k = 0; k < 8; ++k) {
        const int i = t + k * BIN_T;
        if (i < nE) {
            const int pos = boff[myb[k]] + myrank[k];
            stage[pos] = (unsigned)myr[k];
            bkt_of[pos] = (unsigned char)myb[k];
        }
    }
    __syncthreads();

    for (int s = t; s < nE; s += BIN_T) {
        const int b = bkt_of[s];
        pairs[(size_t)b * CAP + gbase[b] + (s - boff[b])] = stage[s];
    }
}

// ---------------- phase 2: per-bucket hist + scan + dense fill + xb ----------

__global__ __launch_bounds__(FILL_T) void k_fill2(const unsigned* __restrict__ pairs,
                                                  const int* __restrict__ gcur,
                                                  const float* __restrict__ x,
                                                  int* __restrict__ offsets,
                                                  float* __restrict__ dinv,
                                                  int* __restrict__ src,
                                                  unsigned short* __restrict__ xb) {
    __shared__ unsigned stage[CAP];      // 64 KB
    __shared__ int ncnt[BKT_NODES];
    __shared__ int ncur[BKT_NODES];
    __shared__ int sc[BKT_NODES];
    __shared__ int scb[256];
    const int b = blockIdx.x, t = threadIdx.x;
    const int base = b << BKT_SHIFT;
    const int nNodes = min(BKT_NODES, N_NODES - base);

    // redundant scan of the 196 bucket counts -> this block's global base
    if (t < 256) scb[t] = (t < NB) ? gcur[t] : 0;
    __syncthreads();
    for (int off = 1; off < 256; off <<= 1) {
        int v = 0;
        if (t < 256 && t >= off) v = scb[t - off];
        __syncthreads();
        if (t < 256) scb[t] += v;
        __syncthreads();
    }
    const int nE = gcur[b];
    const int gb = scb[b] - nE;  // exclusive prefix
    if (b == 0 && t == 0) offsets[N_NODES] = scb[NB - 1];

    const unsigned* bp = pairs + (size_t)b * CAP;
    for (int i = t; i < nE; i += FILL_T) stage[i] = bp[i];
    for (int i = t; i < BKT_NODES; i += FILL_T) ncnt[i] = 0;
    __syncthreads();

    for (int i = t; i < nE; i += FILL_T) atomicAdd(&ncnt[P_DST(stage[i])], 1);
    __syncthreads();

    const int c = (t < BKT_NODES) ? ncnt[t] : 0;
    if (t < BKT_NODES) sc[t] = c;
    __syncthreads();
    for (int off = 1; off < BKT_NODES; off <<= 1) {
        int u = 0;
        if (t < BKT_NODES && t >= off) u = sc[t - off];
        __syncthreads();
        if (t < BKT_NODES) sc[t] += u;
        __syncthreads();
    }
    if (t < BKT_NODES) {
        const int o = gb + sc[t] - c;  // exclusive
        if (t < nNodes) {
            offsets[base + t] = o;
            dinv[base + t] = rsqrtf((float)c + 1.0f);
        }
        ncur[t] = o;
    }
    __syncthreads();

    for (int i = t; i < nE; i += FILL_T) {
        const unsigned u = stage[i];
        const int pos = atomicAdd(&ncur[P_DST(u)], 1);
        src[pos] = P_ROW(u);
    }

    // xb = bf16(dinv * |x|) for this bucket's nodes (ncnt still holds degrees)
    for (int i = t; i < nNodes * (D_IN / 4); i += FILL_T) {
        const int nl = i >> 4;           // local node
        const int q = i & 15;            // float4 index within row
        const float di = rsqrtf((float)ncnt[nl] + 1.0f);
        const float4 v = ((const float4*)(x + (size_t)(base + nl) * D_IN))[q];
        ushort4 o4;
        o4.x = f2bf(di * fabsf(v.x));
        o4.y = f2bf(di * fabsf(v.y));
        o4.z = f2bf(di * fabsf(v.z));
        o4.w = f2bf(di * fabsf(v.w));
        *(ushort4*)(xb + (size_t)(base + nl) * D_IN + q * 4) = o4;
    }
}

// ---------------- fused aggregate + GEMM + epilogue -> z ----------------
// Block: 256 threads (4 waves), 128 nodes, LDS 64 KB -> 2 blocks/CU.
// Phase A: 4 passes; per pass each wave aggregates 8 nodes (slot=lane>>3,
//          dc=lane&7), storing to xs[k][node ^ ((k>>3)<<3)] (2-way banks).
// Phase B: R11 k_gemm body; read base (ty*8) ^ ((k>>3)<<3).
// 256 threads => full VGPR budget (R13 post-mortem: 1024-thread block capped
// VGPRs at 64 and spilled both phases to scratch; 3 GB/dispatch spill traffic).

#define ACC8(v)                                                 \
    do {                                                        \
        a0 += __uint_as_float((v).x << 16);                     \
        a1 += __uint_as_float((v).x & 0xFFFF0000u);             \
        a2 += __uint_as_float((v).y << 16);                     \
        a3 += __uint_as_float((v).y & 0xFFFF0000u);             \
        a4 += __uint_as_float((v).z << 16);                     \
        a5 += __uint_as_float((v).z & 0xFFFF0000u);             \
        a6 += __uint_as_float((v).w << 16);                     \
        a7 += __uint_as_float((v).w & 0xFFFF0000u);             \
    } while (0)

__global__ __launch_bounds__(AG_T) void k_agggemm(const int* __restrict__ offsets,
                                                  const int* __restrict__ src,
                                                  const unsigned short* __restrict__ xb,
                                                  const float* __restrict__ W1,
                                                  const float* __restrict__ dinv,
                                                  const float* __restrict__ b1,
                                                  const float* __restrict__ W2,
                                                  float* __restrict__ z) {
    __shared__ float ws[D_IN * D_HID];     // [k][dim]  32 KB
    __shared__ float xs[D_IN * AG_NODES];  // [k][node] swizzled, 32 KB
    const int t = threadIdx.x;
    const int n0 = blockIdx.x * AG_NODES;

    // stage W1 (2048 float4, 8 per thread)
    {
        const float4* W4 = (const float4*)W1;
        float4* ws4 = (float4*)ws;
#pragma unroll
        for (int i = 0; i < 8; ++i) ws4[t + i * AG_T] = W4[t + i * AG_T];
    }

    // ---- Phase A: aggregation, 4 passes of 32 nodes ----
    const int lane = t & 63;
    const int w = t >> 6;                 // wave 0..3
    const int slot = lane >> 3;           // node slot 0..7
    const int dc = lane & 7;              // dim chunk: dims 8*dc..8*dc+7

#pragma unroll
    for (int pass = 0; pass < 4; ++pass) {
        const int nl = (pass * 4 + w) * 8 + slot;  // local node 0..127
        const int n = n0 + nl;

        float a0 = 0, a1 = 0, a2 = 0, a3 = 0, a4 = 0, a5 = 0, a6 = 0, a7 = 0;

        if (n < N_NODES) {
            {   // self-loop term
                const uint4 v = ((const uint4*)(xb + (size_t)n * D_IN))[dc];
                ACC8(v);
            }
            const int s0 = offsets[n], s1 = offsets[n + 1];
            int j = s0;
            for (; j + 3 < s1; j += 4) {  // 4 gathers in flight per 8-lane group
                const int r0 = src[j];
                const int r1 = src[j + 1];
                const int r2 = src[j + 2];
                const int r3 = src[j + 3];
                const uint4 v0 = ((const uint4*)(xb + (size_t)r0 * D_IN))[dc];
                const uint4 v1 = ((const uint4*)(xb + (size_t)r1 * D_IN))[dc];
                const uint4 v2 = ((const uint4*)(xb + (size_t)r2 * D_IN))[dc];
                const uint4 v3 = ((const uint4*)(xb + (size_t)r3 * D_IN))[dc];
                ACC8(v0);
                ACC8(v1);
                ACC8(v2);
                ACC8(v3);
            }
            for (; j < s1; ++j) {
                const int r = src[j];
                const uint4 v = ((const uint4*)(xb + (size_t)r * D_IN))[dc];
                ACC8(v);
            }
        }

        // transpose to LDS: xs[(8*dc+q)*128 + (nl ^ (dc<<3))] = a_q
        const int xi = nl ^ (dc << 3);
        float* xr = xs + dc * 8 * AG_NODES + xi;
        xr[0 * AG_NODES] = a0;
        xr[1 * AG_NODES] = a1;
        xr[2 * AG_NODES] = a2;
        xr[3 * AG_NODES] = a3;
        xr[4 * AG_NODES] = a4;
        xr[5 * AG_NODES] = a5;
        xr[6 * AG_NODES] = a6;
        xr[7 * AG_NODES] = a7;
    }
    __syncthreads();

    // ---- Phase B: GEMM (R11 structure; 8 nodes x 8 dims per thread) ----
    const int tx = t & 15;   // dims {4tx..4tx+3} and {64+4tx..+3}
    const int ty = t >> 4;   // nodes {ty*8..ty*8+7}

    float acc0[8][4];
    float acc1[8][4];
#pragma unroll
    for (int i = 0; i < 8; ++i)
#pragma unroll
        for (int j = 0; j < 4; ++j) { acc0[i][j] = 0.0f; acc1[i][j] = 0.0f; }

    const float4* ws4 = (const float4*)ws;
#pragma unroll 4
    for (int k = 0; k < D_IN; ++k) {
        const int base = (ty * 8) ^ ((k >> 3) << 3);  // swizzled aligned-8 block
        const float4 xa = *(const float4*)(xs + k * AG_NODES + base);
        const float4 xb_ = *(const float4*)(xs + k * AG_NODES + base + 4);
        const float4 wa = ws4[k * 32 + tx];
        const float4 wb = ws4[k * 32 + 16 + tx];
        const float xn[8] = {xa.x, xa.y, xa.z, xa.w, xb_.x, xb_.y, xb_.z, xb_.w};
#pragma unroll
        for (int i = 0; i < 8; ++i) {
            acc0[i][0] = fmaf(xn[i], wa.x, acc0[i][0]);
            acc0[i][1] = fmaf(xn[i], wa.y, acc0[i][1]);
            acc0[i][2] = fmaf(xn[i], wa.z, acc0[i][2]);
            acc0[i][3] = fmaf(xn[i], wa.w, acc0[i][3]);
            acc1[i][0] = fmaf(xn[i], wb.x, acc1[i][0]);
            acc1[i][1] = fmaf(xn[i], wb.y, acc1[i][1]);
            acc1[i][2] = fmaf(xn[i], wb.z, acc1[i][2]);
            acc1[i][3] = fmaf(xn[i], wb.w, acc1[i][3]);
        }
    }

    // epilogue: h = relu(di*g + b1); sv = h.W2 partial; butterfly over tx lanes
    const float4 b1a = ((const float4*)(b1 + 4 * tx))[0];
    const float4 b1b = ((const float4*)(b1 + 64 + 4 * tx))[0];
    const float4 w2a = ((const float4*)(W2 + 4 * tx))[0];
    const float4 w2b = ((const float4*)(W2 + 64 + 4 * tx))[0];
#pragma unroll
    for (int i = 0; i < 8; ++i) {
        const int nn = n0 + ty * 8 + i;
        if (nn >= N_NODES) continue;
        const float di = dinv[nn];
        float h, sv;
        h = fmaxf(fmaf(di, acc0[i][0], b1a.x), 0.0f); sv = h * w2a.x;
        h = fmaxf(fmaf(di, acc0[i][1], b1a.y), 0.0f); sv = fmaf(h, w2a.y, sv);
        h = fmaxf(fmaf(di, acc0[i][2], b1a.z), 0.0f); sv = fmaf(h, w2a.z, sv);
        h = fmaxf(fmaf(di, acc0[i][3], b1a.w), 0.0f); sv = fmaf(h, w2a.w, sv);
        h = fmaxf(fmaf(di, acc1[i][0], b1b.x), 0.0f); sv = fmaf(h, w2b.x, sv);
        h = fmaxf(fmaf(di, acc1[i][1], b1b.y), 0.0f); sv = fmaf(h, w2b.y, sv);
        h = fmaxf(fmaf(di, acc1[i][2], b1b.z), 0.0f); sv = fmaf(h, w2b.z, sv);
        h = fmaxf(fmaf(di, acc1[i][3], b1b.w), 0.0f); sv = fmaf(h, w2b.w, sv);
#pragma unroll
        for (int m = 1; m <= 8; m <<= 1) sv += __shfl_xor(sv, m, 64);
        if (tx == 0) z[nn] = di * sv;
    }
}

// ---------------- layer 2 aggregate + final ----------------

__global__ void k_out(const int* __restrict__ offsets, const int* __restrict__ src,
                      const float* __restrict__ z, const float* __restrict__ dinv,
                      const float* __restrict__ b2, float* __restrict__ out, int n) {
    const int i = blockIdx.x * blockDim.x + threadIdx.x;
    if (i >= n) return;
    float s = z[i];  // self-loop
    const int s0 = offsets[i], s1 = offsets[i + 1];
    int j = s0;
    for (; j + 3 < s1; j += 4)
        s += z[src[j]] + z[src[j + 1]] + z[src[j + 2]] + z[src[j + 3]];
    for (; j < s1; ++j) s += z[src[j]];
    float v = fmaf(dinv[i], s, b2[0]);
    v = fmaxf(v, 0.0f);
    out[i] = 1.0f / (1.0f + expf(-v));
}

extern "C" void kernel_launch(void* const* d_in, const int* in_sizes, int n_in,
                              void* d_out, int out_size, void* d_ws, size_t ws_size,
                              hipStream_t stream) {
    const float* x  = (const float*)d_in[0];
    const int* ei   = (const int*)d_in[1];
    const float* W1 = (const float*)d_in[2];
    const float* b1 = (const float*)d_in[3];
    const float* W2 = (const float*)d_in[4];
    const float* b2 = (const float*)d_in[5];
    float* out = (float*)d_out;

    const int* row = ei;
    const int* col = ei + N_EDGES;

    // workspace layout
    char* p = (char*)d_ws;
    float* dinv          = (float*)p;          p += sizeof(float) * N_NODES;
    unsigned short* xb   = (unsigned short*)p; p += sizeof(unsigned short) * (size_t)N_NODES * D_IN;
    float* z             = (float*)p;          p += sizeof(float) * N_NODES;
    int* offsets         = (int*)p;            p += sizeof(int) * (N_NODES + 1);
    int* src             = (int*)p;            p += sizeof(int) * N_EDGES;
    int* gcur            = (int*)p;            p += sizeof(int) * NB;
    p = (char*)(((size_t)p + 15) & ~(size_t)15);
    unsigned* pairs      = (unsigned*)p;       p += sizeof(unsigned) * (size_t)NB * CAP;

    hipMemsetAsync(gcur, 0, sizeof(int) * NB, stream);
    k_bin<<<(N_EDGES + CHUNK - 1) / CHUNK, BIN_T, 0, stream>>>(row, col, gcur, pairs);
    k_fill2<<<NB, FILL_T, 0, stream>>>(pairs, gcur, x, offsets, dinv, src, xb);

    k_agggemm<<<AG_NBLK, AG_T, 0, stream>>>(offsets, src, xb, W1, dinv, b1, W2, z);

    k_out<<<(N_NODES + 255) / 256, 256, 0, stream>>>(offsets, src, z, dinv, b2, out, N_NODES);
}

// Round 15
// 99.584 us; speedup vs baseline: 12.6326x; 1.3724x over previous
//
#include <hip/hip_runtime.h>
#include <math.h>

#define N_NODES 100000
#define N_EDGES 1600000
#define D_IN 64
#define D_HID 128

#define BKT_SHIFT 9
#define BKT_NODES 512
#define NB ((N_NODES + BKT_NODES - 1) / BKT_NODES)  // 196
#define CAP 16384                                    // per-bucket capacity (mean ~8163)
#define CHUNK 8192
#define BIN_T 1024
#define FILL_T 1024

#define GM_T 256
#define GM_NODES 128
#define GM_NBLK ((N_NODES + GM_NODES - 1) / GM_NODES)  // 782

// packed edge: bits 0..16 = row (src node), bits 17..25 = dst & 511
#define PACK(row, col) (((unsigned)((col) & (BKT_NODES - 1)) << 17) | (unsigned)(row))
#define P_ROW(u) ((int)((u) & 0x1FFFFu))
#define P_DST(u) ((int)(((u) >> 17) & 0x1FFu))

typedef __attribute__((ext_vector_type(8))) short bf16x8;
typedef __attribute__((ext_vector_type(4))) float f32x4;

static __device__ __forceinline__ unsigned short f2bf(float f) {
    unsigned int u = __float_as_uint(f);
    u += 0x7FFFu + ((u >> 16) & 1u);  // round-to-nearest-even
    return (unsigned short)(u >> 16);
}

// ---------------- phase 1: LDS counting-sort edges into 196 col-buckets ------
// block 0 additionally packs W1 into MFMA B-fragment order (bf16).

__global__ __launch_bounds__(BIN_T) void k_bin(const int* __restrict__ row,
                                               const int* __restrict__ col,
                                               const float* __restrict__ W1,
                                               int* __restrict__ gcur,
                                               unsigned* __restrict__ pairs,
                                               unsigned short* __restrict__ wpack) {
    __shared__ int bcnt[NB];
    __shared__ int boff[NB];
    __shared__ int gbase[NB];
    __shared__ int sc[256];
    __shared__ unsigned stage[CHUNK];          // 32 KB
    __shared__ unsigned char bkt_of[CHUNK];    // 8 KB
    const int t = threadIdx.x;
    const int e0 = blockIdx.x * CHUNK;
    const int nE = min(CHUNK, N_EDGES - e0);

    for (int i = t; i < NB; i += BIN_T) bcnt[i] = 0;
    __syncthreads();

    int myb[8], myrank[8], myr[8];
#pragma unroll
    for (int k = 0; k < 8; ++k) {
        const int i = t + k * BIN_T;
        if (i < nE) {
            myr[k] = row[e0 + i];
            const int c = col[e0 + i];
            myb[k] = c >> BKT_SHIFT;
            myrank[k] = atomicAdd(&bcnt[myb[k]], 1);
            myr[k] = PACK(myr[k], c);
        }
    }
    __syncthreads();

    if (t < 256) sc[t] = (t < NB) ? bcnt[t] : 0;
    __syncthreads();
    for (int off = 1; off < 256; off <<= 1) {
        int v = 0;
        if (t < 256 && t >= off) v = sc[t - off];
        __syncthreads();
        if (t < 256) sc[t] += v;
        __syncthreads();
    }
    if (t < NB) {
        boff[t] = sc[t] - bcnt[t];
        if (bcnt[t] > 0) gbase[t] = atomicAdd(&gcur[t], bcnt[t]);
    }
    __syncthreads();

    // stage into bucket-sorted order in LDS; record bucket per slot inline
#pragma unroll
    for (int k = 0; k < 8; ++k) {
        const int i = t + k * BIN_T;
        if (i < nE) {
            const int pos = boff[myb[k]] + myrank[k];
            stage[pos] = (unsigned)myr[k];
            bkt_of[pos] = (unsigned char)myb[k];
        }
    }
    __syncthreads();

    for (int s = t; s < nE; s += BIN_T) {
        const int b = bkt_of[s];
        pairs[(size_t)b * CAP + gbase[b] + (s - boff[b])] = stage[s];
    }

    // block 0 tail: pack W1 -> B-fragments for mfma_f32_16x16x32_bf16.
    // wpack[((d*2+kk)*64 + l)*8 + j] = bf16(W1[(l>>4)*8 + kk*32 + j][d*16 + (l&15)])
    if (blockIdx.x == 0) {
        for (int idx = t; idx < 8 * 2 * 64 * 8; idx += BIN_T) {
            const int j = idx & 7;
            const int l = (idx >> 3) & 63;
            const int kk = (idx >> 9) & 1;
            const int d = idx >> 10;
            const int krow = (l >> 4) * 8 + kk * 32 + j;
            wpack[idx] = f2bf(W1[krow * D_HID + d * 16 + (l & 15)]);
        }
    }
}

// ---------------- phase 2: per-bucket hist + scan + dense fill + xb ----------

__global__ __launch_bounds__(FILL_T) void k_fill2(const unsigned* __restrict__ pairs,
                                                  const int* __restrict__ gcur,
                                                  const float* __restrict__ x,
                                                  int* __restrict__ offsets,
                                                  float* __restrict__ dinv,
                                                  int* __restrict__ src,
                                                  unsigned short* __restrict__ xb) {
    __shared__ unsigned stage[CAP];      // 64 KB
    __shared__ int ncnt[BKT_NODES];
    __shared__ int ncur[BKT_NODES];
    __shared__ int sc[BKT_NODES];
    __shared__ int scb[256];
    const int b = blockIdx.x, t = threadIdx.x;
    const int base = b << BKT_SHIFT;
    const int nNodes = min(BKT_NODES, N_NODES - base);

    // redundant scan of the 196 bucket counts -> this block's global base
    if (t < 256) scb[t] = (t < NB) ? gcur[t] : 0;
    __syncthreads();
    for (int off = 1; off < 256; off <<= 1) {
        int v = 0;
        if (t < 256 && t >= off) v = scb[t - off];
        __syncthreads();
        if (t < 256) scb[t] += v;
        __syncthreads();
    }
    const int nE = gcur[b];
    const int gb = scb[b] - nE;  // exclusive prefix
    if (b == 0 && t == 0) offsets[N_NODES] = scb[NB - 1];

    const unsigned* bp = pairs + (size_t)b * CAP;
    for (int i = t; i < nE; i += FILL_T) stage[i] = bp[i];
    for (int i = t; i < BKT_NODES; i += FILL_T) ncnt[i] = 0;
    __syncthreads();

    for (int i = t; i < nE; i += FILL_T) atomicAdd(&ncnt[P_DST(stage[i])], 1);
    __syncthreads();

    const int c = (t < BKT_NODES) ? ncnt[t] : 0;
    if (t < BKT_NODES) sc[t] = c;
    __syncthreads();
    for (int off = 1; off < BKT_NODES; off <<= 1) {
        int u = 0;
        if (t < BKT_NODES && t >= off) u = sc[t - off];
        __syncthreads();
        if (t < BKT_NODES) sc[t] += u;
        __syncthreads();
    }
    if (t < BKT_NODES) {
        const int o = gb + sc[t] - c;  // exclusive
        if (t < nNodes) {
            offsets[base + t] = o;
            dinv[base + t] = rsqrtf((float)c + 1.0f);
        }
        ncur[t] = o;
    }
    __syncthreads();

    for (int i = t; i < nE; i += FILL_T) {
        const unsigned u = stage[i];
        const int pos = atomicAdd(&ncur[P_DST(u)], 1);
        src[pos] = P_ROW(u);
    }

    // xb = bf16(dinv * |x|) for this bucket's nodes (ncnt still holds degrees)
    for (int i = t; i < nNodes * (D_IN / 4); i += FILL_T) {
        const int nl = i >> 4;           // local node
        const int q = i & 15;            // float4 index within row
        const float di = rsqrtf((float)ncnt[nl] + 1.0f);
        const float4 v = ((const float4*)(x + (size_t)(base + nl) * D_IN))[q];
        ushort4 o4;
        o4.x = f2bf(di * fabsf(v.x));
        o4.y = f2bf(di * fabsf(v.y));
        o4.z = f2bf(di * fabsf(v.z));
        o4.w = f2bf(di * fabsf(v.w));
        *(ushort4*)(xb + (size_t)(base + nl) * D_IN + q * 4) = o4;
    }
}

// ---------------- aggregate in input space: aggb = bf16(xb[node] + sum xb[src]) --
// 8 nodes per wave: lane = slot(3b) | dim-chunk(3b). No cross-lane reduction.

#define ACC8(v)                                                 \
    do {                                                        \
        a0 += __uint_as_float((v).x << 16);                     \
        a1 += __uint_as_float((v).x & 0xFFFF0000u);             \
        a2 += __uint_as_float((v).y << 16);                     \
        a3 += __uint_as_float((v).y & 0xFFFF0000u);             \
        a4 += __uint_as_float((v).z << 16);                     \
        a5 += __uint_as_float((v).z & 0xFFFF0000u);             \
        a6 += __uint_as_float((v).w << 16);                     \
        a7 += __uint_as_float((v).w & 0xFFFF0000u);             \
    } while (0)

__global__ void k_agg64(const int* __restrict__ offsets, const int* __restrict__ src,
                        const unsigned short* __restrict__ xb,
                        unsigned short* __restrict__ aggb) {
    const int t = blockIdx.x * blockDim.x + threadIdx.x;
    const int lane = t & 63;
    const int slot = lane >> 3;              // node slot 0..7
    const int dc = lane & 7;                 // dim chunk: dims 8*dc .. 8*dc+7
    const int node = (t >> 6) * 8 + slot;    // 8 nodes per wave
    if (node >= N_NODES) return;

    float a0 = 0, a1 = 0, a2 = 0, a3 = 0, a4 = 0, a5 = 0, a6 = 0, a7 = 0;

    {   // self-loop term (all lanes active, coalesced 1 KB per wave)
        const uint4 v = ((const uint4*)(xb + (size_t)node * D_IN))[dc];
        ACC8(v);
    }

    const int s0 = offsets[node], s1 = offsets[node + 1];
    int j = s0;
    for (; j + 3 < s1; j += 4) {  // 4 gathers in flight per 8-lane group (32/wave)
        const int r0 = src[j];
        const int r1 = src[j + 1];
        const int r2 = src[j + 2];
        const int r3 = src[j + 3];
        const uint4 v0 = ((const uint4*)(xb + (size_t)r0 * D_IN))[dc];
        const uint4 v1 = ((const uint4*)(xb + (size_t)r1 * D_IN))[dc];
        const uint4 v2 = ((const uint4*)(xb + (size_t)r2 * D_IN))[dc];
        const uint4 v3 = ((const uint4*)(xb + (size_t)r3 * D_IN))[dc];
        ACC8(v0);
        ACC8(v1);
        ACC8(v2);
        ACC8(v3);
    }
    for (; j < s1; ++j) {
        const int r = src[j];
        const uint4 v = ((const uint4*)(xb + (size_t)r * D_IN))[dc];
        ACC8(v);
    }

    // pack this lane's 8 dims and store (wave writes 1 KB contiguous)
    uint4 w;
    w.x = (unsigned)f2bf(a0) | ((unsigned)f2bf(a1) << 16);
    w.y = (unsigned)f2bf(a2) | ((unsigned)f2bf(a3) << 16);
    w.z = (unsigned)f2bf(a4) | ((unsigned)f2bf(a5) << 16);
    w.w = (unsigned)f2bf(a6) | ((unsigned)f2bf(a7) << 16);
    *(uint4*)(aggb + (size_t)node * D_IN + dc * 8) = w;
}

// ---------------- MFMA GEMM: g = aggb @ W1; h=relu(di*g+b1); z=di*(h.W2) ----
// 256 threads = 4 waves; block covers 128 nodes; wave covers 2 node-blocks of 16.
// mfma_f32_16x16x32_bf16: A lane layout row=lane&15, k=(lane>>4)*8+[0..7];
// B: col=lane&15, k=(lane>>4)*8+[0..7] (pre-packed wpack);
// C/D: col=lane&15, row=(lane>>4)*4+reg  [verified layout, guide §3].

#define EPI(di_, accv, reg, p_)                                            \
    do {                                                                   \
        float h_ = fmaxf(fmaf((di_), (accv)[reg], b1v), 0.0f);             \
        (p_) = fmaf(h_, w2v, (p_));                                        \
    } while (0)

#define RSTORE(p_, di_, nn_)                                               \
    do {                                                                   \
        float sv = (p_);                                                   \
        sv += __shfl_xor(sv, 1, 64);                                       \
        sv += __shfl_xor(sv, 2, 64);                                       \
        sv += __shfl_xor(sv, 4, 64);                                       \
        sv += __shfl_xor(sv, 8, 64);                                       \
        if ((lane & 15) == 0 && (nn_) < N_NODES) z[(nn_)] = (di_) * sv;    \
    } while (0)

__global__ __launch_bounds__(GM_T) void k_gemm(const unsigned short* __restrict__ aggb,
                                               const unsigned short* __restrict__ wpack,
                                               const float* __restrict__ dinv,
                                               const float* __restrict__ b1,
                                               const float* __restrict__ W2,
                                               float* __restrict__ z) {
    const int t = threadIdx.x;
    const int lane = t & 63;
    const int w = t >> 6;                  // wave 0..3
    const int kg = lane >> 4;              // 0..3
    const int n0 = blockIdx.x * GM_NODES;
    const int nbase0 = n0 + (2 * w) * 16;
    const int nbase1 = nbase0 + 16;

    // A fragments (node rows; out-of-range rows read allocated garbage, unused)
    const bf16x8 a00 = *(const bf16x8*)(aggb + (size_t)(nbase0 + (lane & 15)) * D_IN + kg * 8);
    const bf16x8 a01 = *(const bf16x8*)(aggb + (size_t)(nbase0 + (lane & 15)) * D_IN + kg * 8 + 32);
    const bf16x8 a10 = *(const bf16x8*)(aggb + (size_t)(nbase1 + (lane & 15)) * D_IN + kg * 8);
    const bf16x8 a11 = *(const bf16x8*)(aggb + (size_t)(nbase1 + (lane & 15)) * D_IN + kg * 8 + 32);

    // dinv for the epilogue rows this lane owns
    const float di00 = dinv[nbase0 + kg * 4 + 0];
    const float di01 = dinv[nbase0 + kg * 4 + 1];
    const float di02 = dinv[nbase0 + kg * 4 + 2];
    const float di03 = dinv[nbase0 + kg * 4 + 3];
    const float di10 = dinv[nbase1 + kg * 4 + 0];
    const float di11 = dinv[nbase1 + kg * 4 + 1];
    const float di12 = dinv[nbase1 + kg * 4 + 2];
    const float di13 = dinv[nbase1 + kg * 4 + 3];

    float p00 = 0, p01 = 0, p02 = 0, p03 = 0;
    float p10 = 0, p11 = 0, p12 = 0, p13 = 0;

#pragma unroll
    for (int d = 0; d < 8; ++d) {
        const bf16x8 wb0 = *(const bf16x8*)(wpack + ((size_t)(d * 2 + 0) * 64 + lane) * 8);
        const bf16x8 wb1 = *(const bf16x8*)(wpack + ((size_t)(d * 2 + 1) * 64 + lane) * 8);
        f32x4 acc0 = {0.0f, 0.0f, 0.0f, 0.0f};
        acc0 = __builtin_amdgcn_mfma_f32_16x16x32_bf16(a00, wb0, acc0, 0, 0, 0);
        acc0 = __builtin_amdgcn_mfma_f32_16x16x32_bf16(a01, wb1, acc0, 0, 0, 0);
        f32x4 acc1 = {0.0f, 0.0f, 0.0f, 0.0f};
        acc1 = __builtin_amdgcn_mfma_f32_16x16x32_bf16(a10, wb0, acc1, 0, 0, 0);
        acc1 = __builtin_amdgcn_mfma_f32_16x16x32_bf16(a11, wb1, acc1, 0, 0, 0);

        const int cold = d * 16 + (lane & 15);
        const float b1v = b1[cold];
        const float w2v = W2[cold];
        EPI(di00, acc0, 0, p00);
        EPI(di01, acc0, 1, p01);
        EPI(di02, acc0, 2, p02);
        EPI(di03, acc0, 3, p03);
        EPI(di10, acc1, 0, p10);
        EPI(di11, acc1, 1, p11);
        EPI(di12, acc1, 2, p12);
        EPI(di13, acc1, 3, p13);
    }

    RSTORE(p00, di00, nbase0 + kg * 4 + 0);
    RSTORE(p01, di01, nbase0 + kg * 4 + 1);
    RSTORE(p02, di02, nbase0 + kg * 4 + 2);
    RSTORE(p03, di03, nbase0 + kg * 4 + 3);
    RSTORE(p10, di10, nbase1 + kg * 4 + 0);
    RSTORE(p11, di11, nbase1 + kg * 4 + 1);
    RSTORE(p12, di12, nbase1 + kg * 4 + 2);
    RSTORE(p13, di13, nbase1 + kg * 4 + 3);
}

// ---------------- layer 2 aggregate + final ----------------

__global__ void k_out(const int* __restrict__ offsets, const int* __restrict__ src,
                      const float* __restrict__ z, const float* __restrict__ dinv,
                      const float* __restrict__ b2, float* __restrict__ out, int n) {
    const int i = blockIdx.x * blockDim.x + threadIdx.x;
    if (i >= n) return;
    float s = z[i];  // self-loop
    const int s0 = offsets[i], s1 = offsets[i + 1];
    int j = s0;
    for (; j + 3 < s1; j += 4)
        s += z[src[j]] + z[src[j + 1]] + z[src[j + 2]] + z[src[j + 3]];
    for (; j < s1; ++j) s += z[src[j]];
    float v = fmaf(dinv[i], s, b2[0]);
    v = fmaxf(v, 0.0f);
    out[i] = 1.0f / (1.0f + expf(-v));
}

extern "C" void kernel_launch(void* const* d_in, const int* in_sizes, int n_in,
                              void* d_out, int out_size, void* d_ws, size_t ws_size,
                              hipStream_t stream) {
    const float* x  = (const float*)d_in[0];
    const int* ei   = (const int*)d_in[1];
    const float* W1 = (const float*)d_in[2];
    const float* b1 = (const float*)d_in[3];
    const float* W2 = (const float*)d_in[4];
    const float* b2 = (const float*)d_in[5];
    float* out = (float*)d_out;

    const int* row = ei;
    const int* col = ei + N_EDGES;

    // workspace layout
    char* p = (char*)d_ws;
    float* dinv          = (float*)p;          p += sizeof(float) * N_NODES;
    unsigned short* xb   = (unsigned short*)p; p += sizeof(unsigned short) * (size_t)N_NODES * D_IN;
    unsigned short* aggb = (unsigned short*)p; p += sizeof(unsigned short) * (size_t)N_NODES * D_IN;
    float* z             = (float*)p;          p += sizeof(float) * N_NODES;
    int* offsets         = (int*)p;            p += sizeof(int) * (N_NODES + 1);
    int* src             = (int*)p;            p += sizeof(int) * N_EDGES;
    int* gcur            = (int*)p;            p += sizeof(int) * NB;
    p = (char*)(((size_t)p + 15) & ~(size_t)15);
    unsigned short* wpack = (unsigned short*)p; p += sizeof(unsigned short) * 8192;
    p = (char*)(((size_t)p + 15) & ~(size_t)15);
    unsigned* pairs      = (unsigned*)p;       p += sizeof(unsigned) * (size_t)NB * CAP;

    hipMemsetAsync(gcur, 0, sizeof(int) * NB, stream);
    k_bin<<<(N_EDGES + CHUNK - 1) / CHUNK, BIN_T, 0, stream>>>(row, col, W1, gcur, pairs, wpack);
    k_fill2<<<NB, FILL_T, 0, stream>>>(pairs, gcur, x, offsets, dinv, src, xb);

    {
        const long long threads = ((long long)N_NODES + 7) / 8 * 64;
        k_agg64<<<(int)((threads + 255) / 256), 256, 0, stream>>>(offsets, src, xb, aggb);
    }

    k_gemm<<<GM_NBLK, GM_T, 0, stream>>>(aggb, wpack, dinv, b1, W2, z);

    k_out<<<(N_NODES + 255) / 256, 256, 0, stream>>>(offsets, src, z, dinv, b2, out, N_NODES);
}